// Round 18
// baseline (2955.463 us; speedup 1.0000x reference)
//
#include <hip/hip_runtime.h>

typedef unsigned short u16;
typedef unsigned int u32;
typedef unsigned char u8;
typedef __attribute__((ext_vector_type(8))) short short8;
typedef __attribute__((ext_vector_type(8))) char i8x8;
typedef __attribute__((ext_vector_type(4))) int i32x4;
typedef float __attribute__((ext_vector_type(4))) f4;

#define NB 256
#define HID2 2048
#define G4 8192
#define NT0 17            // K0 tiles of 128: [x 96|pad 32][h 2048] = 2176 = 17*128
#define NT1 32            // 4096/128
#define CS 2080           // padded c0 row stride (floats)
#define C1RS (50 * HID2)  // c1 state lives in out_prec slices
// Tiled i8 layouts (all sizes in BYTES): W[kt][8192][128], A[kt][256][128]
#define WT (G4 * 128)
#define AT (NB * 128)
#define A0SZ (NT0 * AT)
#define A1SZ (NT1 * AT)

// quant scales
#define QW 3175.0f                      // 127/0.04
#define QH 127.0f
#define QX 7.9375f                      // 127/16
#define SWH (0.04f / (127.f * 127.f))   // w*h dequant
#define SWX (0.64f / (127.f * 127.f))   // w*x dequant (0.04*16)
#define SH1 (1.f / 127.f)

__device__ __forceinline__ u16 f2b(float f){
  union { float f; u32 u; } v; v.f = f;
  u32 u = v.u;
  u32 r = (u >> 16) & 1u;
  u = u + 0x7fffu + r;
  return (u16)(u >> 16);
}
__device__ __forceinline__ float blo(u32 a){
  union { u32 u; float f; } v; v.u = a << 16; return v.f;
}
__device__ __forceinline__ float bhi(u32 a){
  union { u32 u; float f; } v; v.u = a & 0xffff0000u; return v.f;
}
__device__ __forceinline__ float sigm(float x){ return 1.0f/(1.0f + __expf(-x)); }
__device__ __forceinline__ float tanh_f(float x){ return 1.0f - 2.0f/(1.0f + __expf(2.0f*x)); }
__device__ __forceinline__ char q8(float v, float s){
  int q = (int)rintf(v * s);
  q = q > 127 ? 127 : (q < -127 ? -127 : q);
  return (char)q;
}
__device__ __forceinline__ i32x4 bc(short8 v){
  union { short8 s; i32x4 i; } u; u.s = v; return u.i;
}

__device__ __forceinline__ void gload16(const void* g, void* l){
  __builtin_amdgcn_global_load_lds(
      (const __attribute__((address_space(1))) unsigned int*)g,
      (__attribute__((address_space(3))) unsigned int*)l,
      16, 0, 0);
}

// ---------------- prep kernels ----------------

// W0t[k>>7][n][k&127] i8; k: 0..95 = w_ih0, 96..127 = 0, 128..2175 = w_hh0
__global__ void prep_w0(const float* __restrict__ wih, const float* __restrict__ whh,
                        const float* __restrict__ bih, const float* __restrict__ bhh,
                        char* __restrict__ W0t, float* __restrict__ bias0){
  int n = blockIdx.y;
  int k8 = (blockIdx.x * 256 + threadIdx.x) * 8;
  if (k8 >= 2176) return;
  int u = ((n >> 6) << 4) | (n & 15);
  int gate = (n >> 4) & 3;
  int r = gate * HID2 + u;
  float v[8];
  if (k8 < 96){
    f4 a = __builtin_nontemporal_load((const f4*)(wih + (size_t)r * 96 + k8));
    f4 b = __builtin_nontemporal_load((const f4*)(wih + (size_t)r * 96 + k8 + 4));
    v[0]=a[0]; v[1]=a[1]; v[2]=a[2]; v[3]=a[3]; v[4]=b[0]; v[5]=b[1]; v[6]=b[2]; v[7]=b[3];
  } else if (k8 < 128){
    #pragma unroll
    for (int j = 0; j < 8; ++j) v[j] = 0.0f;
  } else {
    f4 a = __builtin_nontemporal_load((const f4*)(whh + (size_t)r * HID2 + (k8 - 128)));
    f4 b = __builtin_nontemporal_load((const f4*)(whh + (size_t)r * HID2 + (k8 - 128) + 4));
    v[0]=a[0]; v[1]=a[1]; v[2]=a[2]; v[3]=a[3]; v[4]=b[0]; v[5]=b[1]; v[6]=b[2]; v[7]=b[3];
  }
  i8x8 o;
  #pragma unroll
  for (int j = 0; j < 8; ++j) o[j] = q8(v[j], QW);
  *(i8x8*)(W0t + (size_t)(k8 >> 7) * WT + (size_t)n * 128 + (k8 & 127)) = o;
  if (k8 == 0) bias0[n] = bih[r] + bhh[r];
}

// W1t[k>>7][n][k&127] i8; k: 0..2047 = w_ih1 (applied to h0n), 2048.. = w_hh1
__global__ void prep_w1(const float* __restrict__ wih, const float* __restrict__ whh,
                        const float* __restrict__ bih, const float* __restrict__ bhh,
                        char* __restrict__ W1t, float* __restrict__ bias1){
  int n = blockIdx.y;
  int k8 = (blockIdx.x * 256 + threadIdx.x) * 8;
  int u = ((n >> 6) << 4) | (n & 15);
  int gate = (n >> 4) & 3;
  int r = gate * HID2 + u;
  const float* src = (k8 < HID2) ? (wih + (size_t)r * HID2 + k8)
                                 : (whh + (size_t)r * HID2 + (k8 - HID2));
  f4 a = __builtin_nontemporal_load((const f4*)src);
  f4 b = __builtin_nontemporal_load((const f4*)(src + 4));
  i8x8 o;
  o[0]=q8(a[0],QW); o[1]=q8(a[1],QW); o[2]=q8(a[2],QW); o[3]=q8(a[3],QW);
  o[4]=q8(b[0],QW); o[5]=q8(b[1],QW); o[6]=q8(b[2],QW); o[7]=q8(b[3],QW);
  *(i8x8*)(W1t + (size_t)(k8 >> 7) * WT + (size_t)n * 128 + (k8 & 127)) = o;
  if (k8 == 0) bias1[n] = bih[r] + bhh[r];
}

__global__ void prep_wout(const float* __restrict__ wout, u16* __restrict__ WoTb){
  int id = blockIdx.x * 256 + threadIdx.x;   // 96*2048
  int n = id >> 11, k = id & 2047;
  WoTb[(size_t)n * 2048 + k] = f2b(__builtin_nontemporal_load(wout + (size_t)k * 96 + n));
}

// h0/h1/c inits (i8 h states); c1 init staged in out_prec[t=0]
__global__ void prep_state(const float* __restrict__ hs, const float* __restrict__ cs,
                           const float* __restrict__ gts, char* __restrict__ A0_0,
                           char* __restrict__ A1_0, float* __restrict__ c0,
                           float* __restrict__ c1prec){
  int id = blockIdx.x * 256 + threadIdx.x;   // 256*512 threads, 4 elems each
  int b = id >> 9;
  int j = (id & 511) << 2;
  const float* hp = hs + (size_t)b * 49 * HID2 + j;
  const float* cp = cs + (size_t)b * 49 * HID2 + j;
  float sh[4] = {0,0,0,0}, sc[4] = {0,0,0,0};
  for (int t = 0; t < 49; ++t){
    f4 hv = __builtin_nontemporal_load((const f4*)(hp + (size_t)t * HID2));
    f4 cv = __builtin_nontemporal_load((const f4*)(cp + (size_t)t * HID2));
    sh[0]+=hv[0]; sh[1]+=hv[1]; sh[2]+=hv[2]; sh[3]+=hv[3];
    sc[0]+=cv[0]; sc[1]+=cv[1]; sc[2]+=cv[2]; sc[3]+=cv[3];
  }
  f4 gv = __builtin_nontemporal_load((const f4*)(gts + (size_t)b * HID2 + j));
  // h0 at k=128+j -> A0 tile 1+(j>>7); h1 at k=2048+j -> A1 tile 16+(j>>7)
  char* a0p = A0_0 + (size_t)(1 + (j >> 7)) * AT + (size_t)b * 128 + (j & 127);
  char* a1p = A1_0 + (size_t)(16 + (j >> 7)) * AT + (size_t)b * 128 + (j & 127);
  u32 p0 = 0, p1 = 0;
  #pragma unroll
  for (int q = 0; q < 4; ++q){
    float cm = sc[q] / 49.0f;
    c0[(size_t)b * CS + j + q] = cm;
    __builtin_nontemporal_store(cm, c1prec + (size_t)b * C1RS + j + q);
    p0 |= ((u32)(u8)q8(sh[q] / 49.0f, QH)) << (8 * q);
    p1 |= ((u32)(u8)q8((sh[q] + gv[q]) / 50.0f, QH)) << (8 * q);
  }
  *(u32*)a0p = p0;
  *(u32*)a1p = p1;
}

// x init: A0 tile 0 cols 0..95 = q(x); pad cols zeroed in both buffers
__global__ void prep_x(const float* __restrict__ p, char* __restrict__ A0_0,
                       char* __restrict__ A0_1){
  int id = blockIdx.x * 256 + threadIdx.x;  // 256*128
  int b = id >> 7, j = id & 127;
  char v = (j < 96) ? q8(p[(size_t)b * 96 + j], QX) : (char)0;
  A0_0[(size_t)b * 128 + j] = v;
  if (j >= 96) A0_1[(size_t)b * 128 + j] = 0;
}

// ---------------- fused i8 GEMM + LSTM cell ----------------
// r16 structure + K-PHASE ROTATION: block traverses K-tiles in order
// kk = (i + my*(NT/4)) mod NT. i32 accumulation is exact and
// order-independent -> results BIT-IDENTICAL to r16 (absmax must stay
// 0.3828125). Purpose: co-resident blocks (my differs by 2) now request
// different W slabs at any instant and their vmcnt stall windows
// interleave -> breaks the CU-wide lockstep burstiness (the surviving
// theory for the ~1.2 TB/s effective supply after r11/r13/r17 nulls).
// vmcnt ladder unchanged from r16 (queue shape identical): 6/4/0.
template<int NT, bool HAS_X, bool NTC>
__global__ __launch_bounds__(256, 2) void gemm_cell(
    const char* __restrict__ At_, const char* __restrict__ Wt, const float* __restrict__ bias,
    const float* __restrict__ c_in, int ci_rs, float* __restrict__ c_out, int co_rs,
    char* __restrict__ h0o, char* __restrict__ h1o)
{
  __shared__ __align__(16) char ldsW[4][64 * 128];   // 8KB each, 32KB total
  const int tid = threadIdx.x;
  const int id = blockIdx.x;
  const int pn = ((id & 7) << 4) | ((id >> 3) & 15);
  const int my = id >> 7;
  const int m0 = my * 64, n0 = pn * 64;
  const int lane = tid & 63, wid = tid >> 6;
  const int l15 = lane & 15, l4 = lane >> 4;
  const int ar = tid >> 3;            // staging row base 0..31
  const int cb = (tid & 7) << 4;      // staging col byte 0..112
  const int off = my * (NT / 4);      // K-phase rotation per m-tile

  const char* arow = At_ + (size_t)(m0 + wid * 16 + l15) * 128 + l4 * 16;

  i32x4 accH[4], accX[4];
  #pragma unroll
  for (int j = 0; j < 4; ++j){ accH[j] = (i32x4){0,0,0,0}; accX[j] = (i32x4){0,0,0,0}; }

  auto rot = [&](int i) -> int {
    int kk = i + off;
    return kk < NT ? kk : kk - NT;
  };

  auto stageW = [&](int buf, int kt){
    #pragma unroll
    for (int j = 0; j < 2; ++j){
      int r = ar + j * 32;
      const char* src = Wt + ((size_t)kt * G4 + n0 + r) * 128 + (cb ^ ((r & 7) << 4));
      gload16(src, &ldsW[buf][0] + j * 4096 + wid * 1024);
    }
  };

  auto loadA = [&](int kt, short8 (&a)[2]){
    #pragma unroll
    for (int ks = 0; ks < 2; ++ks){
      const char* pa = arow + (size_t)kt * AT + ks * 64;
      asm volatile("global_load_dwordx4 %0, %1, off" : "=&v"(a[ks]) : "v"(pa));
    }
  };

  auto consume = [&](int slot, const short8 (&a)[2], i32x4 (&acc)[4]){
    #pragma unroll
    for (int ks = 0; ks < 2; ++ks){
      i32x4 av = bc(a[ks]);
      #pragma unroll
      for (int nf = 0; nf < 4; ++nf){
        int r = nf * 16 + l15;
        int c = (ks * 64 + (l4 << 4)) ^ ((r & 7) << 4);
        i32x4 wv = *(const i32x4*)(&ldsW[slot][0] + r * 128 + c);
        acc[nf] = __builtin_amdgcn_mfma_i32_16x16x64_i8(av, wv, acc[nf], 0, 0, 0);
      }
    }
  };

  short8 aA[2], aB[2];
  loadA(rot(0), aA);
  stageW(0, rot(0)); stageW(1, rot(1));

  #pragma unroll 1
  for (int i = 0; i < NT; i += 2){
    // ---- even step: consume logical tile rot(i) from slot i&3 ----
    if (i + 1 < NT) loadA(rot(i + 1), aB);
    if (i + 2 < NT){
      stageW((i + 2) & 3, rot(i + 2));
      asm volatile("s_waitcnt vmcnt(6)" ::: "memory");
    } else if (i + 1 < NT){
      asm volatile("s_waitcnt vmcnt(4)" ::: "memory");
    } else {
      asm volatile("s_waitcnt vmcnt(0)" ::: "memory");
    }
    __builtin_amdgcn_sched_barrier(0);
    __builtin_amdgcn_s_barrier();
    __builtin_amdgcn_s_setprio(1);
    if (HAS_X && rot(i) == 0) consume(i & 3, aA, accX);
    else                      consume(i & 3, aA, accH);
    __builtin_amdgcn_s_setprio(0);
    // ---- odd step (guarded: NT may be odd) ----
    const int i2 = i + 1;
    if (i2 < NT){
      if (i2 + 1 < NT) loadA(rot(i2 + 1), aA);
      if (i2 + 2 < NT){
        stageW((i2 + 2) & 3, rot(i2 + 2));
        asm volatile("s_waitcnt vmcnt(6)" ::: "memory");
      } else if (i2 + 1 < NT){
        asm volatile("s_waitcnt vmcnt(4)" ::: "memory");
      } else {
        asm volatile("s_waitcnt vmcnt(0)" ::: "memory");
      }
      __builtin_amdgcn_sched_barrier(0);
      __builtin_amdgcn_s_barrier();
      __builtin_amdgcn_s_setprio(1);
      if (HAS_X && rot(i2) == 0) consume(i2 & 3, aB, accX);
      else                       consume(i2 & 3, aB, accH);
      __builtin_amdgcn_s_setprio(0);
    }
  }

  // epilogue: lane&15 = unit-in-group, nf = gate; dequant then cell
  const int u = pn * 16 + l15;
  float bg[4];
  #pragma unroll
  for (int nf = 0; nf < 4; ++nf) bg[nf] = bias[n0 + nf * 16 + l15];
  const int mb = m0 + wid * 16 + (l4 << 2);
  #pragma unroll
  for (int reg = 0; reg < 4; ++reg){
    const int m = mb + reg;
    float g[4];
    #pragma unroll
    for (int nf = 0; nf < 4; ++nf){
      float v = (float)accH[nf][reg] * SWH;
      if (HAS_X) v += (float)accX[nf][reg] * SWX;
      g[nf] = v + bg[nf];
    }
    float iv = sigm(g[0]), fv = sigm(g[1]), ov = sigm(g[3]);
    float gv = tanh_f(g[2]);
    float co = c_in[(size_t)m * ci_rs + u];
    float cn = fv * co + iv * gv;
    float hn = ov * tanh_f(cn);
    if (NTC) __builtin_nontemporal_store(cn, c_out + (size_t)m * co_rs + u);
    else     c_out[(size_t)m * co_rs + u] = cn;
    char hb = (char)(int)rintf(hn * QH);
    size_t oidx = (size_t)(u >> 7) * AT + (size_t)m * 128 + (u & 127);
    h0o[oidx] = hb;
    if (h1o) h1o[oidx] = hb;
  }
}

// ---------------- output projection: 1 block per batch row ----------------
__global__ __launch_bounds__(256) void proj_step(const char* __restrict__ h1t, // tiled i8 (base = tile 16 of A1w)
                                                 const u16* __restrict__ WoTb,
                                                 const float* __restrict__ bout,
                                                 const float* __restrict__ p,
                                                 float* __restrict__ out_pre, int t,
                                                 char* __restrict__ A0w){
  __shared__ __align__(16) char hl[2048];   // 2 KB h1 row (i8)
  __shared__ float part[2][128];
  const int b = blockIdx.x;
  const int tid = threadIdx.x;
  // gather row b: u = tid*8 -> tile tid>>4, col (tid&15)*8
  *(i8x8*)&hl[tid * 8] =
      *(const i8x8*)(h1t + (size_t)(tid >> 4) * AT + (size_t)b * 128 + (tid & 15) * 8);
  __syncthreads();
  const int n = tid & 127;
  const int kc = tid >> 7;
  float acc = 0.0f;
  if (n < 96){
    const u16* wrow = WoTb + (size_t)n * 2048 + kc * 1024;
    const char* hrow = hl + kc * 1024;
    for (int k = 0; k < 1024; k += 8){
      i8x8 hv = *(const i8x8*)(hrow + k);
      uint4 wv = *(const uint4*)(wrow + k);
      acc += (float)hv[0] * blo(wv.x) + (float)hv[1] * bhi(wv.x)
           + (float)hv[2] * blo(wv.y) + (float)hv[3] * bhi(wv.y)
           + (float)hv[4] * blo(wv.z) + (float)hv[5] * bhi(wv.z)
           + (float)hv[6] * blo(wv.w) + (float)hv[7] * bhi(wv.w);
    }
  }
  part[kc][n] = acc;
  __syncthreads();
  if (tid < 96){
    float s = (part[0][tid] + part[1][tid]) * SH1 + bout[tid];
    s += (t == 0) ? p[(size_t)b * 96 + tid]
                  : out_pre[((size_t)b * 50 + (t - 1)) * 96 + tid];
    __builtin_nontemporal_store(s, out_pre + ((size_t)b * 50 + t) * 96 + tid);
    A0w[(size_t)b * 128 + tid] = q8(s, QX);   // x tile 0, col tid
  }
}

// ---------------- launcher ----------------
extern "C" void kernel_launch(void* const* d_in, const int* in_sizes, int n_in,
                              void* d_out, int out_size, void* d_ws, size_t ws_size,
                              hipStream_t stream){
  const float* hs   = (const float*)d_in[0];
  const float* cs   = (const float*)d_in[1];
  const float* gts  = (const float*)d_in[2];
  const float* p    = (const float*)d_in[4];
  const float* wih0 = (const float*)d_in[6];
  const float* whh0 = (const float*)d_in[7];
  const float* bih0 = (const float*)d_in[8];
  const float* bhh0 = (const float*)d_in[9];
  const float* wih1 = (const float*)d_in[10];
  const float* whh1 = (const float*)d_in[11];
  const float* bih1 = (const float*)d_in[12];
  const float* bhh1 = (const float*)d_in[13];
  const float* wout = (const float*)d_in[14];
  const float* bout = (const float*)d_in[15];

  char* w = (char*)d_ws;
  auto take = [&](size_t bytes) -> char* {
    char* r = w; w += (bytes + 255) & ~(size_t)255; return r;
  };
  char*  W0t   = take((size_t)NT0 * WT);
  char*  W1t   = take((size_t)NT1 * WT);
  float* bias0 = (float*)take((size_t)G4 * 4);
  float* bias1 = (float*)take((size_t)G4 * 4);
  char*  A0    = take((size_t)2 * A0SZ);
  char*  A1    = take((size_t)2 * A1SZ);
  float* c0    = (float*)take((size_t)NB * CS * 4);
  u16*   WoTb  = (u16*)take((size_t)96 * HID2 * 2);
  if ((size_t)(w - (char*)d_ws) > ws_size) return;

  float* out_pre  = (float*)d_out;                    // [B][50][96]
  float* out_prec = out_pre + (size_t)NB * 50 * 96;   // [B][50][2048]

  prep_w0<<<dim3(2, G4), 256, 0, stream>>>(wih0, whh0, bih0, bhh0, W0t, bias0);
  prep_w1<<<dim3(2, G4), 256, 0, stream>>>(wih1, whh1, bih1, bhh1, W1t, bias1);
  prep_wout<<<768, 256, 0, stream>>>(wout, WoTb);
  prep_state<<<512, 256, 0, stream>>>(hs, cs, gts, A0, A1, c0, out_prec);
  prep_x<<<128, 256, 0, stream>>>(p, A0, A0 + A0SZ);

  for (int t = 0; t < 50; ++t){
    char* A0r = A0 + (size_t)(t & 1) * A0SZ;
    char* A0w = A0 + (size_t)((t + 1) & 1) * A0SZ;
    char* A1r = A1 + (size_t)(t & 1) * A1SZ;
    char* A1w = A1 + (size_t)((t + 1) & 1) * A1SZ;

    // layer 0: reads A0r (tile0=x | tiles1-16=h0), writes h0n ->
    //          A1r tiles 0..15 and self-feedback -> A0w tiles 1..16
    gemm_cell<NT0, true, false><<<512, 256, 0, stream>>>(A0r, W0t, bias0,
        c0, CS, c0, CS,
        A1r, A0w + AT);

    // layer 1: reads A1r (h0n tiles 0-15 | h1 tiles 16-31); c1 in out_prec
    const float* c1in = out_prec + (size_t)(t ? t - 1 : 0) * HID2;
    gemm_cell<NT1, false, true><<<512, 256, 0, stream>>>(A1r, W1t, bias1,
        c1in, C1RS, out_prec + (size_t)t * HID2, C1RS,
        A1w + 16 * AT, (char*)nullptr);

    // projection: pre = h1n @ Wout + bias_out + prev ; writes next x
    proj_step<<<256, 256, 0, stream>>>(A1w + 16 * AT, WoTb, bout, p, out_pre, t, A0w);
  }
}

// Round 19
// 2807.129 us; speedup vs baseline: 1.0528x; 1.0528x over previous
//
#include <hip/hip_runtime.h>

typedef unsigned short u16;
typedef unsigned int u32;
typedef unsigned char u8;
typedef __attribute__((ext_vector_type(8))) short short8;
typedef __attribute__((ext_vector_type(8))) char i8x8;
typedef __attribute__((ext_vector_type(4))) int i32x4;
typedef float __attribute__((ext_vector_type(4))) f4;

#define NB 256
#define HID2 2048
#define G4 8192
#define NT0 17            // K0 tiles of 128: [x 96|pad 32][h 2048] = 2176 = 17*128
#define NT1 32            // 4096/128
#define CS 2080           // padded c0 row stride (floats)
#define C1RS (50 * HID2)  // c1 state lives in out_prec slices
// Tiled i8 layouts (all sizes in BYTES): W[kt][8192][128], A[kt][256][128]
#define WT (G4 * 128)
#define AT (NB * 128)
#define A0SZ (NT0 * AT)
#define A1SZ (NT1 * AT)

// quant scales
#define QW 3175.0f                      // 127/0.04
#define QH 127.0f
#define QX 7.9375f                      // 127/16
#define SWH (0.04f / (127.f * 127.f))   // w*h dequant
#define SWX (0.64f / (127.f * 127.f))   // w*x dequant (0.04*16)
#define SH1 (1.f / 127.f)

__device__ __forceinline__ u16 f2b(float f){
  union { float f; u32 u; } v; v.f = f;
  u32 u = v.u;
  u32 r = (u >> 16) & 1u;
  u = u + 0x7fffu + r;
  return (u16)(u >> 16);
}
__device__ __forceinline__ float blo(u32 a){
  union { u32 u; float f; } v; v.u = a << 16; return v.f;
}
__device__ __forceinline__ float bhi(u32 a){
  union { u32 u; float f; } v; v.u = a & 0xffff0000u; return v.f;
}
__device__ __forceinline__ float sigm(float x){ return 1.0f/(1.0f + __expf(-x)); }
__device__ __forceinline__ float tanh_f(float x){ return 1.0f - 2.0f/(1.0f + __expf(2.0f*x)); }
__device__ __forceinline__ char q8(float v, float s){
  int q = (int)rintf(v * s);
  q = q > 127 ? 127 : (q < -127 ? -127 : q);
  return (char)q;
}
__device__ __forceinline__ i32x4 bc(short8 v){
  union { short8 s; i32x4 i; } u; u.s = v; return u.i;
}

__device__ __forceinline__ void gload16(const void* g, void* l){
  __builtin_amdgcn_global_load_lds(
      (const __attribute__((address_space(1))) unsigned int*)g,
      (__attribute__((address_space(3))) unsigned int*)l,
      16, 0, 0);
}

// ---------------- prep kernels ----------------

// W0t[k>>7][n][k&127] i8; k: 0..95 = w_ih0, 96..127 = 0, 128..2175 = w_hh0
__global__ void prep_w0(const float* __restrict__ wih, const float* __restrict__ whh,
                        const float* __restrict__ bih, const float* __restrict__ bhh,
                        char* __restrict__ W0t, float* __restrict__ bias0){
  int n = blockIdx.y;
  int k8 = (blockIdx.x * 256 + threadIdx.x) * 8;
  if (k8 >= 2176) return;
  int u = ((n >> 6) << 4) | (n & 15);
  int gate = (n >> 4) & 3;
  int r = gate * HID2 + u;
  float v[8];
  if (k8 < 96){
    f4 a = __builtin_nontemporal_load((const f4*)(wih + (size_t)r * 96 + k8));
    f4 b = __builtin_nontemporal_load((const f4*)(wih + (size_t)r * 96 + k8 + 4));
    v[0]=a[0]; v[1]=a[1]; v[2]=a[2]; v[3]=a[3]; v[4]=b[0]; v[5]=b[1]; v[6]=b[2]; v[7]=b[3];
  } else if (k8 < 128){
    #pragma unroll
    for (int j = 0; j < 8; ++j) v[j] = 0.0f;
  } else {
    f4 a = __builtin_nontemporal_load((const f4*)(whh + (size_t)r * HID2 + (k8 - 128)));
    f4 b = __builtin_nontemporal_load((const f4*)(whh + (size_t)r * HID2 + (k8 - 128) + 4));
    v[0]=a[0]; v[1]=a[1]; v[2]=a[2]; v[3]=a[3]; v[4]=b[0]; v[5]=b[1]; v[6]=b[2]; v[7]=b[3];
  }
  i8x8 o;
  #pragma unroll
  for (int j = 0; j < 8; ++j) o[j] = q8(v[j], QW);
  *(i8x8*)(W0t + (size_t)(k8 >> 7) * WT + (size_t)n * 128 + (k8 & 127)) = o;
  if (k8 == 0) bias0[n] = bih[r] + bhh[r];
}

// W1t[k>>7][n][k&127] i8; k: 0..2047 = w_ih1 (applied to h0n), 2048.. = w_hh1
__global__ void prep_w1(const float* __restrict__ wih, const float* __restrict__ whh,
                        const float* __restrict__ bih, const float* __restrict__ bhh,
                        char* __restrict__ W1t, float* __restrict__ bias1){
  int n = blockIdx.y;
  int k8 = (blockIdx.x * 256 + threadIdx.x) * 8;
  int u = ((n >> 6) << 4) | (n & 15);
  int gate = (n >> 4) & 3;
  int r = gate * HID2 + u;
  const float* src = (k8 < HID2) ? (wih + (size_t)r * HID2 + k8)
                                 : (whh + (size_t)r * HID2 + (k8 - HID2));
  f4 a = __builtin_nontemporal_load((const f4*)src);
  f4 b = __builtin_nontemporal_load((const f4*)(src + 4));
  i8x8 o;
  o[0]=q8(a[0],QW); o[1]=q8(a[1],QW); o[2]=q8(a[2],QW); o[3]=q8(a[3],QW);
  o[4]=q8(b[0],QW); o[5]=q8(b[1],QW); o[6]=q8(b[2],QW); o[7]=q8(b[3],QW);
  *(i8x8*)(W1t + (size_t)(k8 >> 7) * WT + (size_t)n * 128 + (k8 & 127)) = o;
  if (k8 == 0) bias1[n] = bih[r] + bhh[r];
}

__global__ void prep_wout(const float* __restrict__ wout, u16* __restrict__ WoTb){
  int id = blockIdx.x * 256 + threadIdx.x;   // 96*2048
  int n = id >> 11, k = id & 2047;
  WoTb[(size_t)n * 2048 + k] = f2b(__builtin_nontemporal_load(wout + (size_t)k * 96 + n));
}

// h0/h1/c inits (i8 h states); c1 init staged in out_prec[t=0]
__global__ void prep_state(const float* __restrict__ hs, const float* __restrict__ cs,
                           const float* __restrict__ gts, char* __restrict__ A0_0,
                           char* __restrict__ A1_0, float* __restrict__ c0,
                           float* __restrict__ c1prec){
  int id = blockIdx.x * 256 + threadIdx.x;   // 256*512 threads, 4 elems each
  int b = id >> 9;
  int j = (id & 511) << 2;
  const float* hp = hs + (size_t)b * 49 * HID2 + j;
  const float* cp = cs + (size_t)b * 49 * HID2 + j;
  float sh[4] = {0,0,0,0}, sc[4] = {0,0,0,0};
  for (int t = 0; t < 49; ++t){
    f4 hv = __builtin_nontemporal_load((const f4*)(hp + (size_t)t * HID2));
    f4 cv = __builtin_nontemporal_load((const f4*)(cp + (size_t)t * HID2));
    sh[0]+=hv[0]; sh[1]+=hv[1]; sh[2]+=hv[2]; sh[3]+=hv[3];
    sc[0]+=cv[0]; sc[1]+=cv[1]; sc[2]+=cv[2]; sc[3]+=cv[3];
  }
  f4 gv = __builtin_nontemporal_load((const f4*)(gts + (size_t)b * HID2 + j));
  // h0 at k=128+j -> A0 tile 1+(j>>7); h1 at k=2048+j -> A1 tile 16+(j>>7)
  char* a0p = A0_0 + (size_t)(1 + (j >> 7)) * AT + (size_t)b * 128 + (j & 127);
  char* a1p = A1_0 + (size_t)(16 + (j >> 7)) * AT + (size_t)b * 128 + (j & 127);
  u32 p0 = 0, p1 = 0;
  #pragma unroll
  for (int q = 0; q < 4; ++q){
    float cm = sc[q] / 49.0f;
    c0[(size_t)b * CS + j + q] = cm;
    __builtin_nontemporal_store(cm, c1prec + (size_t)b * C1RS + j + q);
    p0 |= ((u32)(u8)q8(sh[q] / 49.0f, QH)) << (8 * q);
    p1 |= ((u32)(u8)q8((sh[q] + gv[q]) / 50.0f, QH)) << (8 * q);
  }
  *(u32*)a0p = p0;
  *(u32*)a1p = p1;
}

// x init: A0 tile 0 cols 0..95 = q(x); pad cols zeroed in both buffers
__global__ void prep_x(const float* __restrict__ p, char* __restrict__ A0_0,
                       char* __restrict__ A0_1){
  int id = blockIdx.x * 256 + threadIdx.x;  // 256*128
  int b = id >> 7, j = id & 127;
  char v = (j < 96) ? q8(p[(size_t)b * 96 + j], QX) : (char)0;
  A0_0[(size_t)b * 128 + j] = v;
  if (j >= 96) A0_1[(size_t)b * 128 + j] = 0;
}

// ---------------- fused i8 GEMM + LSTM cell ----------------
// r16 exactly (best: 2811 us). BM=64/BN=64, 256 threads, grid 512,
// 2 blocks/CU; tiled W slabs -> LDS 4-buffer rotation, ONE barrier per
// K-step, reg-A, XOR swizzle, i8 MFMA (K-tile 128 = two K=64 MFMAs),
// i32 exact accumulate. vmcnt derived: steady 6, tail 4, last 0.
template<int NT, bool HAS_X, bool NTC>
__global__ __launch_bounds__(256, 2) void gemm_cell(
    const char* __restrict__ At_, const char* __restrict__ Wt, const float* __restrict__ bias,
    const float* __restrict__ c_in, int ci_rs, float* __restrict__ c_out, int co_rs,
    char* __restrict__ h0o, char* __restrict__ h1o)
{
  __shared__ __align__(16) char ldsW[4][64 * 128];   // 8KB each, 32KB total
  const int tid = threadIdx.x;
  const int id = blockIdx.x;
  const int pn = ((id & 7) << 4) | ((id >> 3) & 15);
  const int my = id >> 7;
  const int m0 = my * 64, n0 = pn * 64;
  const int lane = tid & 63, wid = tid >> 6;
  const int l15 = lane & 15, l4 = lane >> 4;
  const int ar = tid >> 3;            // staging row base 0..31
  const int cb = (tid & 7) << 4;      // staging col byte 0..112

  const char* arow = At_ + (size_t)(m0 + wid * 16 + l15) * 128 + l4 * 16;

  i32x4 accH[4], accX[4];
  #pragma unroll
  for (int j = 0; j < 4; ++j){ accH[j] = (i32x4){0,0,0,0}; accX[j] = (i32x4){0,0,0,0}; }

  auto stageW = [&](int buf, int kt){
    #pragma unroll
    for (int j = 0; j < 2; ++j){
      int r = ar + j * 32;
      const char* src = Wt + ((size_t)kt * G4 + n0 + r) * 128 + (cb ^ ((r & 7) << 4));
      gload16(src, &ldsW[buf][0] + j * 4096 + wid * 1024);
    }
  };

  auto loadA = [&](int kt, short8 (&a)[2]){
    #pragma unroll
    for (int ks = 0; ks < 2; ++ks){
      const char* pa = arow + (size_t)kt * AT + ks * 64;
      asm volatile("global_load_dwordx4 %0, %1, off" : "=&v"(a[ks]) : "v"(pa));
    }
  };

  auto consume = [&](int slot, const short8 (&a)[2], i32x4 (&acc)[4]){
    #pragma unroll
    for (int ks = 0; ks < 2; ++ks){
      i32x4 av = bc(a[ks]);
      #pragma unroll
      for (int nf = 0; nf < 4; ++nf){
        int r = nf * 16 + l15;
        int c = (ks * 64 + (l4 << 4)) ^ ((r & 7) << 4);
        i32x4 wv = *(const i32x4*)(&ldsW[slot][0] + r * 128 + c);
        acc[nf] = __builtin_amdgcn_mfma_i32_16x16x64_i8(av, wv, acc[nf], 0, 0, 0);
      }
    }
  };

  short8 aA[2], aB[2];
  loadA(0, aA);
  stageW(0, 0); stageW(1, 1);

  #pragma unroll 1
  for (int kt = 0; kt < NT; kt += 2){
    // ---- even step: consume aA ----
    if (kt + 1 < NT) loadA(kt + 1, aB);
    if (kt + 2 < NT){
      stageW((kt + 2) & 3, kt + 2);
      asm volatile("s_waitcnt vmcnt(6)" ::: "memory");
    } else if (kt + 1 < NT){
      asm volatile("s_waitcnt vmcnt(4)" ::: "memory");
    } else {
      asm volatile("s_waitcnt vmcnt(0)" ::: "memory");
    }
    __builtin_amdgcn_sched_barrier(0);
    __builtin_amdgcn_s_barrier();
    __builtin_amdgcn_s_setprio(1);
    if (HAS_X && kt == 0) consume(0, aA, accX);
    else                  consume(kt & 3, aA, accH);
    __builtin_amdgcn_s_setprio(0);
    // ---- odd step (guarded: NT may be odd) ----
    const int k2 = kt + 1;
    if (k2 < NT){
      if (k2 + 1 < NT) loadA(k2 + 1, aA);
      if (k2 + 2 < NT){
        stageW((k2 + 2) & 3, k2 + 2);
        asm volatile("s_waitcnt vmcnt(6)" ::: "memory");
      } else if (k2 + 1 < NT){
        asm volatile("s_waitcnt vmcnt(4)" ::: "memory");
      } else {
        asm volatile("s_waitcnt vmcnt(0)" ::: "memory");
      }
      __builtin_amdgcn_sched_barrier(0);
      __builtin_amdgcn_s_barrier();
      __builtin_amdgcn_s_setprio(1);
      consume(k2 & 3, aB, accH);
      __builtin_amdgcn_s_setprio(0);
    }
  }

  // epilogue: lane&15 = unit-in-group, nf = gate; dequant then cell
  const int u = pn * 16 + l15;
  float bg[4];
  #pragma unroll
  for (int nf = 0; nf < 4; ++nf) bg[nf] = bias[n0 + nf * 16 + l15];
  const int mb = m0 + wid * 16 + (l4 << 2);
  #pragma unroll
  for (int reg = 0; reg < 4; ++reg){
    const int m = mb + reg;
    float g[4];
    #pragma unroll
    for (int nf = 0; nf < 4; ++nf){
      float v = (float)accH[nf][reg] * SWH;
      if (HAS_X) v += (float)accX[nf][reg] * SWX;
      g[nf] = v + bg[nf];
    }
    float iv = sigm(g[0]), fv = sigm(g[1]), ov = sigm(g[3]);
    float gv = tanh_f(g[2]);
    float co = c_in[(size_t)m * ci_rs + u];
    float cn = fv * co + iv * gv;
    float hn = ov * tanh_f(cn);
    if (NTC) __builtin_nontemporal_store(cn, c_out + (size_t)m * co_rs + u);
    else     c_out[(size_t)m * co_rs + u] = cn;
    char hb = (char)(int)rintf(hn * QH);
    size_t oidx = (size_t)(u >> 7) * AT + (size_t)m * 128 + (u & 127);
    h0o[oidx] = hb;
    if (h1o) h1o[oidx] = hb;
  }
}

// ---------------- output projection: 1 block per batch row ----------------
__global__ __launch_bounds__(256) void proj_step(const char* __restrict__ h1t, // tiled i8 (base = tile 16 of A1w)
                                                 const u16* __restrict__ WoTb,
                                                 const float* __restrict__ bout,
                                                 const float* __restrict__ p,
                                                 float* __restrict__ out_pre, int t,
                                                 char* __restrict__ A0w){
  __shared__ __align__(16) char hl[2048];   // 2 KB h1 row (i8)
  __shared__ float part[2][128];
  const int b = blockIdx.x;
  const int tid = threadIdx.x;
  // gather row b: u = tid*8 -> tile tid>>4, col (tid&15)*8
  *(i8x8*)&hl[tid * 8] =
      *(const i8x8*)(h1t + (size_t)(tid >> 4) * AT + (size_t)b * 128 + (tid & 15) * 8);
  __syncthreads();
  const int n = tid & 127;
  const int kc = tid >> 7;
  float acc = 0.0f;
  if (n < 96){
    const u16* wrow = WoTb + (size_t)n * 2048 + kc * 1024;
    const char* hrow = hl + kc * 1024;
    for (int k = 0; k < 1024; k += 8){
      i8x8 hv = *(const i8x8*)(hrow + k);
      uint4 wv = *(const uint4*)(wrow + k);
      acc += (float)hv[0] * blo(wv.x) + (float)hv[1] * bhi(wv.x)
           + (float)hv[2] * blo(wv.y) + (float)hv[3] * bhi(wv.y)
           + (float)hv[4] * blo(wv.z) + (float)hv[5] * bhi(wv.z)
           + (float)hv[6] * blo(wv.w) + (float)hv[7] * bhi(wv.w);
    }
  }
  part[kc][n] = acc;
  __syncthreads();
  if (tid < 96){
    float s = (part[0][tid] + part[1][tid]) * SH1 + bout[tid];
    s += (t == 0) ? p[(size_t)b * 96 + tid]
                  : out_pre[((size_t)b * 50 + (t - 1)) * 96 + tid];
    __builtin_nontemporal_store(s, out_pre + ((size_t)b * 50 + t) * 96 + tid);
    A0w[(size_t)b * 128 + tid] = q8(s, QX);   // x tile 0, col tid
  }
}

// ---------------- launcher ----------------
extern "C" void kernel_launch(void* const* d_in, const int* in_sizes, int n_in,
                              void* d_out, int out_size, void* d_ws, size_t ws_size,
                              hipStream_t stream){
  const float* hs   = (const float*)d_in[0];
  const float* cs   = (const float*)d_in[1];
  const float* gts  = (const float*)d_in[2];
  const float* p    = (const float*)d_in[4];
  const float* wih0 = (const float*)d_in[6];
  const float* whh0 = (const float*)d_in[7];
  const float* bih0 = (const float*)d_in[8];
  const float* bhh0 = (const float*)d_in[9];
  const float* wih1 = (const float*)d_in[10];
  const float* whh1 = (const float*)d_in[11];
  const float* bih1 = (const float*)d_in[12];
  const float* bhh1 = (const float*)d_in[13];
  const float* wout = (const float*)d_in[14];
  const float* bout = (const float*)d_in[15];

  char* w = (char*)d_ws;
  auto take = [&](size_t bytes) -> char* {
    char* r = w; w += (bytes + 255) & ~(size_t)255; return r;
  };
  char*  W0t   = take((size_t)NT0 * WT);
  char*  W1t   = take((size_t)NT1 * WT);
  float* bias0 = (float*)take((size_t)G4 * 4);
  float* bias1 = (float*)take((size_t)G4 * 4);
  char*  A0    = take((size_t)2 * A0SZ);
  char*  A1    = take((size_t)2 * A1SZ);
  float* c0    = (float*)take((size_t)NB * CS * 4);
  u16*   WoTb  = (u16*)take((size_t)96 * HID2 * 2);
  if ((size_t)(w - (char*)d_ws) > ws_size) return;

  float* out_pre  = (float*)d_out;                    // [B][50][96]
  float* out_prec = out_pre + (size_t)NB * 50 * 96;   // [B][50][2048]

  prep_w0<<<dim3(2, G4), 256, 0, stream>>>(wih0, whh0, bih0, bhh0, W0t, bias0);
  prep_w1<<<dim3(2, G4), 256, 0, stream>>>(wih1, whh1, bih1, bhh1, W1t, bias1);
  prep_wout<<<768, 256, 0, stream>>>(wout, WoTb);
  prep_state<<<512, 256, 0, stream>>>(hs, cs, gts, A0, A1, c0, out_prec);
  prep_x<<<128, 256, 0, stream>>>(p, A0, A0 + A0SZ);

  for (int t = 0; t < 50; ++t){
    char* A0r = A0 + (size_t)(t & 1) * A0SZ;
    char* A0w = A0 + (size_t)((t + 1) & 1) * A0SZ;
    char* A1r = A1 + (size_t)(t & 1) * A1SZ;
    char* A1w = A1 + (size_t)((t + 1) & 1) * A1SZ;

    // layer 0: reads A0r (tile0=x | tiles1-16=h0), writes h0n ->
    //          A1r tiles 0..15 and self-feedback -> A0w tiles 1..16
    gemm_cell<NT0, true, false><<<512, 256, 0, stream>>>(A0r, W0t, bias0,
        c0, CS, c0, CS,
        A1r, A0w + AT);

    // layer 1: reads A1r (h0n tiles 0-15 | h1 tiles 16-31); c1 in out_prec
    const float* c1in = out_prec + (size_t)(t ? t - 1 : 0) * HID2;
    gemm_cell<NT1, false, true><<<512, 256, 0, stream>>>(A1r, W1t, bias1,
        c1in, C1RS, out_prec + (size_t)t * HID2, C1RS,
        A1w + 16 * AT, (char*)nullptr);

    // projection: pre = h1n @ Wout + bias_out + prev ; writes next x
    proj_step<<<256, 256, 0, stream>>>(A1w + 16 * AT, WoTb, bout, p, out_pre, t, A0w);
  }
}